// Round 13
// baseline (207.335 us; speedup 1.0000x reference)
//
#include <hip/hip_runtime.h>
#include <math.h>

#define N_EL    16
#define N_NUC   4
#define N_FEATS 32
#define N_PAIRS 184
#define HIDDEN  64
#define TB      64           // batch elements per block (2 M-tiles of 32)
#define BLOCK   256
#define DLD     185          // dist LDS stride
#define H1LD    68           // h1 stride (inside reused dist region)
#define KP      46           // pairs per K-wave (4*46 = 184)

typedef _Float16 half8  __attribute__((ext_vector_type(8)));
typedef __fp16   fp16x2 __attribute__((ext_vector_type(2)));  // cvt_pkrtz ret type
typedef float    floatx16 __attribute__((ext_vector_type(16)));

__device__ __forceinline__ float exp2_raw(float x) {
    float r;
    asm("v_exp_f32 %0, %1" : "=v"(r) : "v"(x));
    return r;
}

// triu_indices(16, 1)
__constant__ unsigned char c_I[120] = {
    0,0,0,0,0,0,0,0,0,0,0,0,0,0,0,
    1,1,1,1,1,1,1,1,1,1,1,1,1,1,
    2,2,2,2,2,2,2,2,2,2,2,2,2,
    3,3,3,3,3,3,3,3,3,3,3,3,
    4,4,4,4,4,4,4,4,4,4,4,
    5,5,5,5,5,5,5,5,5,5,
    6,6,6,6,6,6,6,6,6,
    7,7,7,7,7,7,7,7,
    8,8,8,8,8,8,8,
    9,9,9,9,9,9,
    10,10,10,10,10,
    11,11,11,11,
    12,12,12,
    13,13,
    14
};
__constant__ unsigned char c_J[120] = {
    1,2,3,4,5,6,7,8,9,10,11,12,13,14,15,
    2,3,4,5,6,7,8,9,10,11,12,13,14,15,
    3,4,5,6,7,8,9,10,11,12,13,14,15,
    4,5,6,7,8,9,10,11,12,13,14,15,
    5,6,7,8,9,10,11,12,13,14,15,
    6,7,8,9,10,11,12,13,14,15,
    7,8,9,10,11,12,13,14,15,
    8,9,10,11,12,13,14,15,
    9,10,11,12,13,14,15,
    10,11,12,13,14,15,
    11,12,13,14,15,
    12,13,14,15,
    13,14,15,
    14,15,
    15
};

__device__ __forceinline__ float ssp(float x) {
    float a = fabsf(x);
    return fmaxf(x, 0.0f) + log1pf(__expf(-a)) - 0.69314718056f;
}
__device__ __forceinline__ float redg(float v) {
    v += __shfl_xor(v, 1);
    v += __shfl_xor(v, 2);
    v += __shfl_xor(v, 4);
    return v;
}

// ---------------------------------------------------------------------------
// Prep (unchanged, verified R7-R12): W1 -> fp16 32x32x16 B-fragment order.
// ---------------------------------------------------------------------------
__global__ __launch_bounds__(256)
void prep_w1_kernel(const float* __restrict__ W1, half8* __restrict__ ws)
{
    __shared__ float w[N_FEATS * HIDDEN];   // 8 KB: one pair's rows
    const int p = blockIdx.x;
    const float* src = W1 + (size_t)p * (N_FEATS * HIDDEN);
    for (int k = threadIdx.x; k < N_FEATS * HIDDEN; k += 256) w[k] = src[k];
    __syncthreads();

    const int tid  = threadIdx.x;
    const int lane = tid & 63;
    const int cidx = tid >> 6;              // kb*2 + nh
    const int nh = cidx & 1, kb = cidx >> 1;
    const int krow = kb * 16 + (lane >> 5) * 8;
    const int n    = nh * 32 + (lane & 31);
    half8 h;
#pragma unroll
    for (int j = 0; j < 8; ++j) h[j] = (_Float16)w[(krow + j) * 64 + n];
    ws[(size_t)p * 256 + tid] = h;
}

// ---------------------------------------------------------------------------
// Main: block = 64 elements (2 M-tiles), 4 waves; wave kh owns BOTH tiles x
// all 64 cols over pairs [kh*46, kh*46+46). R12 post-mortem: waves are ~97%
// latency-stalled with pipes ~12% busy -> double independent work per wave
// (2 A-frag sets, 8 MFMAs reusing the same 4 B-frags) and halve block count.
// ---------------------------------------------------------------------------
__global__ __launch_bounds__(BLOCK)
void wfnet_kernel(const float* __restrict__ rs,
                  const float* __restrict__ coords,
                  const float* __restrict__ charges,
                  const half8* __restrict__ ws,
                  const float* __restrict__ b1,
                  const float* __restrict__ W2,
                  const float* __restrict__ b2,
                  const float* __restrict__ W3,
                  const float* __restrict__ b3,
                  float* __restrict__ out)
{
    __shared__ float lds_rs[TB * N_EL * 3];   // 12 KB
    __shared__ float lds_dist[TB * DLD];      // 47.4 KB; reused as red/h1 later

    const int tid  = threadIdx.x;
    const int wave = tid >> 6;               // = kh
    const int lane = tid & 63;
    const int m    = lane & 31;              // element row within tile
    const int lh   = lane >> 5;              // k-half within fragment

    // ---- phase 1: stage rs ----
    {
        const float* rs_blk = rs + (size_t)blockIdx.x * (TB * N_EL * 3);
        for (int k = tid; k < TB * N_EL * 3; k += BLOCK) lds_rs[k] = rs_blk[k];
    }
    __syncthreads();

    // ---- phase 2: distances for both halves; asy partials in registers ----
    float asyA = 0.0f, asyB = 0.0f;
    {
        const int bl = tid >> 3, g = tid & 7;
        const float4 ch = *(const float4*)charges;
#pragma unroll
        for (int h = 0; h < 2; ++h) {
            const int el = h * 32 + bl;
            const float* myrs = lds_rs + el * (N_EL * 3);
            float* dst = lds_dist + el * DLD;
            float asy = 0.0f;
            for (int i = 0; i < 8; ++i) {
                const int p = g + 8 * i;
                const int e = p >> 2, n = p & 3;
                const float dx = myrs[e * 3 + 0] - coords[n * 3 + 0];
                const float dy = myrs[e * 3 + 1] - coords[n * 3 + 1];
                const float dz = myrs[e * 3 + 2] - coords[n * 3 + 2];
                const float d = sqrtf(dx * dx + dy * dy + dz * dz);
                dst[p] = d;
                const float Z = (n < 2) ? ((n == 0) ? ch.x : ch.y)
                                        : ((n == 2) ? ch.z : ch.w);
                asy += (Z * d + d * d) / (1.0f + d);   // decay = 1
            }
            for (int i = 0; i < 15; ++i) {
                const int q  = g + 8 * i;
                const int ei = 3 * (int)c_I[q], ej = 3 * (int)c_J[q];
                const float dx = myrs[ei + 0] - myrs[ej + 0];
                const float dy = myrs[ei + 1] - myrs[ej + 1];
                const float dz = myrs[ei + 2] - myrs[ej + 2];
                dst[64 + q] = sqrtf(dx * dx + dy * dy + dz * dz);
            }
            if (h == 0) asyA = asy; else asyB = asy;
        }
    }
    __syncthreads();

    // per-lane Gaussian constants: x = 2^(-(d*P1+P0)^2), S = sqrt(log2 e)
    const int f0 = lh * 8;
#define MKC(P, FF) float P##1, P##0; { \
    const float fq = (float)(FF) * (1.0f / 31.0f); \
    const float mu = 10.0f * fq * fq; \
    const float is = 7.0f / (1.0f + 10.0f * fq); \
    P##1 = is * 1.2011224087864498f; \
    P##0 = -mu * P##1; }
    MKC(C0_, f0 + 0) MKC(C1_, f0 + 1) MKC(C2_, f0 + 2) MKC(C3_, f0 + 3)
    MKC(C4_, f0 + 4) MKC(C5_, f0 + 5) MKC(C6_, f0 + 6) MKC(C7_, f0 + 7)
    MKC(D0_, f0 + 16) MKC(D1_, f0 + 17) MKC(D2_, f0 + 18) MKC(D3_, f0 + 19)
    MKC(D4_, f0 + 20) MKC(D5_, f0 + 21) MKC(D6_, f0 + 22) MKC(D7_, f0 + 23)
#undef MKC

    // ---- K loop: 46 pairs, unroll x2, dual fragment sets, 2 M-tiles ----
    floatx16 a0A = {}, a0B = {};   // tile0 cols 0..31 / 32..63
    floatx16 a1A = {}, a1B = {};   // tile1
    const half8* wq = ws + ((size_t)(wave * KP) * 256 + lane);
    const float* drow0 = lds_dist + m * DLD + wave * KP;
    const float* drow1 = drow0 + 32 * DLD;

#define XT(dd, P) ({ const float t_ = fmaf(dd, P##1, P##0); exp2_raw(t_ * -t_); })
#define MKA(U, V, dd) \
    union { half8 v; fp16x2 h[4]; } U, V; \
    U.h[0] = __builtin_amdgcn_cvt_pkrtz(XT(dd, C0_), XT(dd, C1_)); \
    U.h[1] = __builtin_amdgcn_cvt_pkrtz(XT(dd, C2_), XT(dd, C3_)); \
    U.h[2] = __builtin_amdgcn_cvt_pkrtz(XT(dd, C4_), XT(dd, C5_)); \
    U.h[3] = __builtin_amdgcn_cvt_pkrtz(XT(dd, C6_), XT(dd, C7_)); \
    V.h[0] = __builtin_amdgcn_cvt_pkrtz(XT(dd, D0_), XT(dd, D1_)); \
    V.h[1] = __builtin_amdgcn_cvt_pkrtz(XT(dd, D2_), XT(dd, D3_)); \
    V.h[2] = __builtin_amdgcn_cvt_pkrtz(XT(dd, D4_), XT(dd, D5_)); \
    V.h[3] = __builtin_amdgcn_cvt_pkrtz(XT(dd, D6_), XT(dd, D7_));
#define KROUND2(dx0, dx1, Q0, Q1, Q2, Q3) { \
    MKA(u0, v0, dx0) \
    MKA(u1, v1, dx1) \
    a0A = __builtin_amdgcn_mfma_f32_32x32x16_f16(u0.v, Q0, a0A, 0, 0, 0); \
    a0B = __builtin_amdgcn_mfma_f32_32x32x16_f16(u0.v, Q1, a0B, 0, 0, 0); \
    a1A = __builtin_amdgcn_mfma_f32_32x32x16_f16(u1.v, Q0, a1A, 0, 0, 0); \
    a1B = __builtin_amdgcn_mfma_f32_32x32x16_f16(u1.v, Q1, a1B, 0, 0, 0); \
    a0A = __builtin_amdgcn_mfma_f32_32x32x16_f16(v0.v, Q2, a0A, 0, 0, 0); \
    a0B = __builtin_amdgcn_mfma_f32_32x32x16_f16(v0.v, Q3, a0B, 0, 0, 0); \
    a1A = __builtin_amdgcn_mfma_f32_32x32x16_f16(v1.v, Q2, a1A, 0, 0, 0); \
    a1B = __builtin_amdgcn_mfma_f32_32x32x16_f16(v1.v, Q3, a1B, 0, 0, 0); \
}

    half8 pA0 = wq[0],   pA1 = wq[64],  pA2 = wq[128], pA3 = wq[192];
    half8 pB0 = wq[256], pB1 = wq[320], pB2 = wq[384], pB3 = wq[448];
    float d00 = drow0[0], d01 = drow0[1];
    float d10 = drow1[0], d11 = drow1[1];

    for (int it = 0; it < 22; ++it) {       // rounds 0..43 with prefetch
        const float e00 = drow0[2 * it + 2], e01 = drow0[2 * it + 3];
        const float e10 = drow1[2 * it + 2], e11 = drow1[2 * it + 3];
        const half8* wn = wq + 512;

        KROUND2(d00, d10, pA0, pA1, pA2, pA3);   // even round
        pA0 = wn[0];  pA1 = wn[64];  pA2 = wn[128]; pA3 = wn[192];

        KROUND2(d01, d11, pB0, pB1, pB2, pB3);   // odd round
        pB0 = wn[256]; pB1 = wn[320]; pB2 = wn[384]; pB3 = wn[448];

        wq = wn;
        d00 = e00; d01 = e01; d10 = e10; d11 = e11;
    }
    KROUND2(d00, d10, pA0, pA1, pA2, pA3);       // round 44
    KROUND2(d01, d11, pB0, pB1, pB2, pB3);       // round 45
#undef KROUND2
#undef MKA
#undef XT

    __syncthreads();   // K done -> dist region reused as red/h1 (47 KB)
    float* lds_red = lds_dist;
    // dump slots: ((srcwave-2)*2 + tile)*2048 floats; 4 slots = 32 KB

    // ---- kh reduction. C/D: col = lane&31 (+nh*32),
    //      row el = (rg&3) + 8*(rg>>2) + 4*lh (+ tile*32) ----
    if (wave >= 2) {
        float* dst = lds_red + (wave - 2) * 4096;
#pragma unroll
        for (int rg = 0; rg < 16; ++rg) {
            const int el = (rg & 3) + 8 * (rg >> 2) + 4 * lh;
            dst[el * 64 + m]             = a0A[rg];
            dst[el * 64 + 32 + m]        = a0B[rg];
            dst[2048 + el * 64 + m]      = a1A[rg];
            dst[2048 + el * 64 + 32 + m] = a1B[rg];
        }
    }
    __syncthreads();
    if (wave < 2) {   // wave0 += wave2's dump, wave1 += wave3's dump
        const float* srcr = lds_red + wave * 4096;
#pragma unroll
        for (int rg = 0; rg < 16; ++rg) {
            const int el = (rg & 3) + 8 * (rg >> 2) + 4 * lh;
            a0A[rg] += srcr[el * 64 + m];
            a0B[rg] += srcr[el * 64 + 32 + m];
            a1A[rg] += srcr[2048 + el * 64 + m];
            a1B[rg] += srcr[2048 + el * 64 + 32 + m];
        }
    }
    __syncthreads();
    if (wave == 1) {
#pragma unroll
        for (int rg = 0; rg < 16; ++rg) {
            const int el = (rg & 3) + 8 * (rg >> 2) + 4 * lh;
            lds_red[el * 64 + m]             = a0A[rg];
            lds_red[el * 64 + 32 + m]        = a0B[rg];
            lds_red[2048 + el * 64 + m]      = a1A[rg];
            lds_red[2048 + el * 64 + 32 + m] = a1B[rg];
        }
    }
    __syncthreads();
    if (wave == 0) {
        const float bA = b1[m], bB = b1[32 + m];
        // ALL reads first (both tiles), then all writes: the h1 layout
        // (64*68 floats) overlaps the dump slots being read, and only
        // within-wave in-order LDS guarantees read-before-write here.
#pragma unroll
        for (int rg = 0; rg < 16; ++rg) {
            const int el = (rg & 3) + 8 * (rg >> 2) + 4 * lh;
            a0A[rg] += lds_red[el * 64 + m];
            a0B[rg] += lds_red[el * 64 + 32 + m];
            a1A[rg] += lds_red[2048 + el * 64 + m];
            a1B[rg] += lds_red[2048 + el * 64 + 32 + m];
        }
#pragma unroll
        for (int rg = 0; rg < 16; ++rg) {
            const int el = (rg & 3) + 8 * (rg >> 2) + 4 * lh;
            lds_red[el * H1LD + m]             = ssp(a0A[rg] + bA);
            lds_red[el * H1LD + 32 + m]        = ssp(a0B[rg] + bB);
            lds_red[(32 + el) * H1LD + m]      = ssp(a1A[rg] + bA);
            lds_red[(32 + el) * H1LD + 32 + m] = ssp(a1B[rg] + bB);
        }
    }
    __syncthreads();

    // ---- tail: layers 2/3, two element-halves per thread group ----
    const int b_local = tid >> 3;
    const int g       = tid & 7;
    const float4* __restrict__ W2v = (const float4*)W2;
    const float4* __restrict__ b2v = (const float4*)b2;
    const float4* __restrict__ W3v = (const float4*)W3;
    const int wbi = g * 2;
    const float4 b2a = b2v[wbi], b2b = b2v[wbi + 1];
    const float4 w3a = W3v[wbi], w3b = W3v[wbi + 1];

#pragma unroll
    for (int h = 0; h < 2; ++h) {
        const int el = h * 32 + b_local;
        const int b  = blockIdx.x * TB + el;
        float asy = redg(h == 0 ? asyA : asyB);

        float s0 = b2a.x, s1 = b2a.y, s2 = b2a.z, s3 = b2a.w;
        float s4 = b2b.x, s5 = b2b.y, s6 = b2b.z, s7 = b2b.w;
        const float* __restrict__ h1row = lds_red + el * H1LD;
        for (int k = 0; k < HIDDEN; ++k) {
            const float hk  = h1row[k];
            const float4 wa = W2v[k * 16 + wbi];
            const float4 wb = W2v[k * 16 + wbi + 1];
            s0 = fmaf(hk, wa.x, s0); s1 = fmaf(hk, wa.y, s1);
            s2 = fmaf(hk, wa.z, s2); s3 = fmaf(hk, wa.w, s3);
            s4 = fmaf(hk, wb.x, s4); s5 = fmaf(hk, wb.y, s5);
            s6 = fmaf(hk, wb.z, s6); s7 = fmaf(hk, wb.w, s7);
        }
        float part = ssp(s0) * w3a.x + ssp(s1) * w3a.y
                   + ssp(s2) * w3a.z + ssp(s3) * w3a.w
                   + ssp(s4) * w3b.x + ssp(s5) * w3b.y
                   + ssp(s6) * w3b.z + ssp(s7) * w3b.w;
        part = redg(part);
        if (g == 0) {
            const float ys = part + b3[0];
            out[b] = __expf(ys) * __expf(-asy);
        }
    }
}

extern "C" void kernel_launch(void* const* d_in, const int* in_sizes, int n_in,
                              void* d_out, int out_size, void* d_ws, size_t ws_size,
                              hipStream_t stream) {
    const float* rs      = (const float*)d_in[0];
    const float* coords  = (const float*)d_in[1];
    const float* charges = (const float*)d_in[2];
    const float* W1      = (const float*)d_in[3];
    const float* b1      = (const float*)d_in[4];
    const float* W2      = (const float*)d_in[5];
    const float* b2      = (const float*)d_in[6];
    const float* W3      = (const float*)d_in[7];
    const float* b3      = (const float*)d_in[8];
    float* out = (float*)d_out;

    const int batch = in_sizes[0] / (N_EL * 3);   // 32768
    half8* ws = (half8*)d_ws;                     // 736 KB scratch

    prep_w1_kernel<<<N_PAIRS, 256, 0, stream>>>(W1, ws);
    wfnet_kernel<<<batch / TB, BLOCK, 0, stream>>>(rs, coords, charges, ws,
                                                   b1, W2, b2, W3, b3, out);
}

// Round 14
// 158.090 us; speedup vs baseline: 1.3115x; 1.3115x over previous
//
#include <hip/hip_runtime.h>
#include <math.h>

#define N_EL    16
#define N_NUC   4
#define N_FEATS 32
#define N_PAIRS 184
#define HIDDEN  64
#define TB      32           // batch elements per block
#define BLOCK   256
#define DLD     185          // dist LDS stride
#define H1LD    68           // h1 stride (inside reused dist region)
#define TPW     23           // K-tiles (2 pairs each) per wave; 4*23*2 = 184

typedef int   intx8    __attribute__((ext_vector_type(8)));
typedef float floatx16 __attribute__((ext_vector_type(16)));

__device__ __forceinline__ float exp2_raw(float x) {
    float r;
    asm("v_exp_f32 %0, %1" : "=v"(r) : "v"(x));
    return r;
}

// triu_indices(16, 1)
__constant__ unsigned char c_I[120] = {
    0,0,0,0,0,0,0,0,0,0,0,0,0,0,0,
    1,1,1,1,1,1,1,1,1,1,1,1,1,1,
    2,2,2,2,2,2,2,2,2,2,2,2,2,
    3,3,3,3,3,3,3,3,3,3,3,3,
    4,4,4,4,4,4,4,4,4,4,4,
    5,5,5,5,5,5,5,5,5,5,
    6,6,6,6,6,6,6,6,6,
    7,7,7,7,7,7,7,7,
    8,8,8,8,8,8,8,
    9,9,9,9,9,9,
    10,10,10,10,10,
    11,11,11,11,
    12,12,12,
    13,13,
    14
};
__constant__ unsigned char c_J[120] = {
    1,2,3,4,5,6,7,8,9,10,11,12,13,14,15,
    2,3,4,5,6,7,8,9,10,11,12,13,14,15,
    3,4,5,6,7,8,9,10,11,12,13,14,15,
    4,5,6,7,8,9,10,11,12,13,14,15,
    5,6,7,8,9,10,11,12,13,14,15,
    6,7,8,9,10,11,12,13,14,15,
    7,8,9,10,11,12,13,14,15,
    8,9,10,11,12,13,14,15,
    9,10,11,12,13,14,15,
    10,11,12,13,14,15,
    11,12,13,14,15,
    12,13,14,15,
    13,14,15,
    14,15,
    15
};

__device__ __forceinline__ float ssp(float x) {
    float a = fabsf(x);
    return fmaxf(x, 0.0f) + log1pf(__expf(-a)) - 0.69314718056f;
}
__device__ __forceinline__ float redg(float v) {
    v += __shfl_xor(v, 1);
    v += __shfl_xor(v, 2);
    v += __shfl_xor(v, 4);
    return v;
}

// ---------------------------------------------------------------------------
// Prep: W1 -> fp8 e4m3 (pre-scaled by 2^6; MFMA applies 2^-6 via scale_b)
// in 32x32x64 B-fragment order. One block per K-tile t (pairs 2t, 2t+1).
// Fragment chunk = ws[(t*2+nh)*64 + lane] (32 B): byte j (j = reg*4+b) holds
// B[k][n] with n = nh*32 + (lane&31) and k-permutation
//   j 0..15  -> pair 2t,   feat (lane>>5)*16 + j
//   j 16..31 -> pair 2t+1, feat (lane>>5)*16 + (j-16)
// (A-side uses the same permutation -- dot product invariant under it.)
// ---------------------------------------------------------------------------
__global__ __launch_bounds__(256)
void prep_w1_kernel(const float* __restrict__ W1, intx8* __restrict__ ws)
{
    __shared__ float w[2 * N_FEATS * HIDDEN];   // 16 KB: two pairs' rows
    const int t = blockIdx.x;
    const float* src = W1 + (size_t)(2 * t) * (N_FEATS * HIDDEN);
    for (int k = threadIdx.x; k < 2 * N_FEATS * HIDDEN; k += 256) w[k] = src[k];
    __syncthreads();

    const int tid = threadIdx.x;
    if (tid >= 128) return;
    const int lane = tid & 63;
    const int nh   = tid >> 6;
    const int lh   = lane >> 5;
    const int col  = nh * 32 + (lane & 31);
    const int fb   = lh * 16;
    intx8 frag;
#pragma unroll
    for (int r = 0; r < 8; ++r) {
        const int pair = r >> 2;                   // 0..1 within tile
        const int fo   = fb + ((r & 3) << 2);      // feature of byte 0
        const float v0 = 64.0f * w[(pair * N_FEATS + fo + 0) * 64 + col];
        const float v1 = 64.0f * w[(pair * N_FEATS + fo + 1) * 64 + col];
        const float v2 = 64.0f * w[(pair * N_FEATS + fo + 2) * 64 + col];
        const float v3 = 64.0f * w[(pair * N_FEATS + fo + 3) * 64 + col];
        int d = __builtin_amdgcn_cvt_pk_fp8_f32(v0, v1, 0, false);
        d     = __builtin_amdgcn_cvt_pk_fp8_f32(v2, v3, d, true);
        frag[r] = d;
    }
    ws[(size_t)(t * 2 + nh) * 64 + lane] = frag;
}

// ---------------------------------------------------------------------------
// Main: R12 geometry (TB=32, 4 waves, 1024 blocks, 16 waves/CU) with the
// K loop on mfma_scale_f32_32x32x64_f8f6f4: 2 pairs per round -> 23 rounds
// (vs 46). R13 lesson: wall ~ rounds x structural latency / waves-per-CU;
// this halves rounds at unchanged occupancy. scale_a=127 (x1),
// scale_b=121 (x2^-6, undoes prep's 2^6).
// ---------------------------------------------------------------------------
__global__ __launch_bounds__(BLOCK)
void wfnet_kernel(const float* __restrict__ rs,
                  const float* __restrict__ coords,
                  const float* __restrict__ charges,
                  const intx8* __restrict__ ws,
                  const float* __restrict__ b1,
                  const float* __restrict__ W2,
                  const float* __restrict__ b2,
                  const float* __restrict__ W3,
                  const float* __restrict__ b3,
                  float* __restrict__ out)
{
    __shared__ float lds_rs[TB * N_EL * 3];   // 6 KB
    __shared__ float lds_dist[TB * DLD];      // 23.7 KB; reused as red/h1 later

    const int tid  = threadIdx.x;
    const int wave = tid >> 6;               // = kh
    const int lane = tid & 63;
    const int m    = lane & 31;              // element row
    const int lh   = lane >> 5;              // k-half within fragment

    // ---- phase 1: stage rs ----
    {
        const float* rs_blk = rs + (size_t)blockIdx.x * (TB * N_EL * 3);
        for (int k = tid; k < TB * N_EL * 3; k += BLOCK) lds_rs[k] = rs_blk[k];
    }
    __syncthreads();

    // ---- phase 2: distances -> lds_dist; asy partial stays in a register ----
    float asy = 0.0f;
    {
        const int bl = tid >> 3, g = tid & 7;
        const float* myrs = lds_rs + bl * (N_EL * 3);
        float* dst = lds_dist + bl * DLD;
        const float4 ch = *(const float4*)charges;
        for (int i = 0; i < 8; ++i) {
            const int p = g + 8 * i;
            const int e = p >> 2, n = p & 3;
            const float dx = myrs[e * 3 + 0] - coords[n * 3 + 0];
            const float dy = myrs[e * 3 + 1] - coords[n * 3 + 1];
            const float dz = myrs[e * 3 + 2] - coords[n * 3 + 2];
            const float d = sqrtf(dx * dx + dy * dy + dz * dz);
            dst[p] = d;
            const float Z = (n < 2) ? ((n == 0) ? ch.x : ch.y)
                                    : ((n == 2) ? ch.z : ch.w);
            asy += (Z * d + d * d) / (1.0f + d);   // decay = sqrt(2*0.5) = 1
        }
        for (int i = 0; i < 15; ++i) {
            const int q  = g + 8 * i;
            const int ei = 3 * (int)c_I[q], ej = 3 * (int)c_J[q];
            const float dx = myrs[ei + 0] - myrs[ej + 0];
            const float dy = myrs[ei + 1] - myrs[ej + 1];
            const float dz = myrs[ei + 2] - myrs[ej + 2];
            dst[64 + q] = sqrtf(dx * dx + dy * dy + dz * dz);
        }
    }
    __syncthreads();

    // per-lane Gaussian constants for feats lh*16 .. lh*16+15:
    // x = 2^(-(d*P1+P0)^2), S = sqrt(log2 e)
    const int f0 = lh * 16;
#define MKC(P, FF) float P##1, P##0; { \
    const float fq = (float)(FF) * (1.0f / 31.0f); \
    const float mu = 10.0f * fq * fq; \
    const float is = 7.0f / (1.0f + 10.0f * fq); \
    P##1 = is * 1.2011224087864498f; \
    P##0 = -mu * P##1; }
    MKC(F0_,  f0 + 0)  MKC(F1_,  f0 + 1)  MKC(F2_,  f0 + 2)  MKC(F3_,  f0 + 3)
    MKC(F4_,  f0 + 4)  MKC(F5_,  f0 + 5)  MKC(F6_,  f0 + 6)  MKC(F7_,  f0 + 7)
    MKC(F8_,  f0 + 8)  MKC(F9_,  f0 + 9)  MKC(F10_, f0 + 10) MKC(F11_, f0 + 11)
    MKC(F12_, f0 + 12) MKC(F13_, f0 + 13) MKC(F14_, f0 + 14) MKC(F15_, f0 + 15)
#undef MKC

    // ---- K loop: 23 rounds of 2 pairs, dual B-frag sets, no barriers ----
    floatx16 accA = {};   // cols 0..31
    floatx16 accB = {};   // cols 32..63
    const intx8* wq = ws + ((size_t)(wave * TPW) * 128 + lane);
    const float* drow = lds_dist + m * DLD + wave * (2 * TPW);

#define XO(dd, P) ({ const float t_ = fmaf(dd, P##1, P##0); exp2_raw(t_ * -t_); })
#define MKA8(AV, dx0, dx1) \
    intx8 AV; { int dw_; \
    dw_   = __builtin_amdgcn_cvt_pk_fp8_f32(XO(dx0,F0_),  XO(dx0,F1_),  0,  false); \
    AV[0] = __builtin_amdgcn_cvt_pk_fp8_f32(XO(dx0,F2_),  XO(dx0,F3_),  dw_, true); \
    dw_   = __builtin_amdgcn_cvt_pk_fp8_f32(XO(dx0,F4_),  XO(dx0,F5_),  0,  false); \
    AV[1] = __builtin_amdgcn_cvt_pk_fp8_f32(XO(dx0,F6_),  XO(dx0,F7_),  dw_, true); \
    dw_   = __builtin_amdgcn_cvt_pk_fp8_f32(XO(dx0,F8_),  XO(dx0,F9_),  0,  false); \
    AV[2] = __builtin_amdgcn_cvt_pk_fp8_f32(XO(dx0,F10_), XO(dx0,F11_), dw_, true); \
    dw_   = __builtin_amdgcn_cvt_pk_fp8_f32(XO(dx0,F12_), XO(dx0,F13_), 0,  false); \
    AV[3] = __builtin_amdgcn_cvt_pk_fp8_f32(XO(dx0,F14_), XO(dx0,F15_), dw_, true); \
    dw_   = __builtin_amdgcn_cvt_pk_fp8_f32(XO(dx1,F0_),  XO(dx1,F1_),  0,  false); \
    AV[4] = __builtin_amdgcn_cvt_pk_fp8_f32(XO(dx1,F2_),  XO(dx1,F3_),  dw_, true); \
    dw_   = __builtin_amdgcn_cvt_pk_fp8_f32(XO(dx1,F4_),  XO(dx1,F5_),  0,  false); \
    AV[5] = __builtin_amdgcn_cvt_pk_fp8_f32(XO(dx1,F6_),  XO(dx1,F7_),  dw_, true); \
    dw_   = __builtin_amdgcn_cvt_pk_fp8_f32(XO(dx1,F8_),  XO(dx1,F9_),  0,  false); \
    AV[6] = __builtin_amdgcn_cvt_pk_fp8_f32(XO(dx1,F10_), XO(dx1,F11_), dw_, true); \
    dw_   = __builtin_amdgcn_cvt_pk_fp8_f32(XO(dx1,F12_), XO(dx1,F13_), 0,  false); \
    AV[7] = __builtin_amdgcn_cvt_pk_fp8_f32(XO(dx1,F14_), XO(dx1,F15_), dw_, true); }
#define KROUND(AV, Q0, Q1) { \
    accA = __builtin_amdgcn_mfma_scale_f32_32x32x64_f8f6f4( \
               AV, Q0, accA, 0, 0, 0, 0x7F7F7F7F, 0, 0x79797979); \
    accB = __builtin_amdgcn_mfma_scale_f32_32x32x64_f8f6f4( \
               AV, Q1, accB, 0, 0, 0, 0x7F7F7F7F, 0, 0x79797979); }

    intx8 pA0 = wq[0],   pA1 = wq[64];
    intx8 pB0 = wq[128], pB1 = wq[192];
    float dA0 = drow[0], dA1 = drow[1];
    float dB0 = drow[2], dB1 = drow[3];

    for (int it = 0; it < 10; ++it) {        // rounds 0..19, prefetch +2
        const intx8* wn = wq + 256;
        const float eA0 = drow[4 * it + 4], eA1 = drow[4 * it + 5];
        const float eB0 = drow[4 * it + 6], eB1 = drow[4 * it + 7];

        { MKA8(av, dA0, dA1) KROUND(av, pA0, pA1) }   // round 2it
        pA0 = wn[0]; pA1 = wn[64];

        { MKA8(bv, dB0, dB1) KROUND(bv, pB0, pB1) }   // round 2it+1
        pB0 = wn[128]; pB1 = wn[192];

        wq = wn;
        dA0 = eA0; dA1 = eA1; dB0 = eB0; dB1 = eB1;
    }
    {   // rounds 20, 21, 22
        const intx8* wn = wq + 256;
        const float eA0 = drow[44], eA1 = drow[45];
        { MKA8(av, dA0, dA1) KROUND(av, pA0, pA1) }   // round 20
        pA0 = wn[0]; pA1 = wn[64];
        { MKA8(bv, dB0, dB1) KROUND(bv, pB0, pB1) }   // round 21
        { MKA8(cv, eA0, eA1) KROUND(cv, pA0, pA1) }   // round 22
    }
#undef KROUND
#undef MKA8
#undef XO

    __syncthreads();   // all K-loops done -> dist region reused as red/h1
    float* lds_red = lds_dist;   // 16 KB red region + h1 live inside it

    // ---- kh reduction. C/D (shape-determined, same as 32x32 bf16):
    //      col = lane&31 (+nh*32), row el = (rg&3) + 8*(rg>>2) + 4*lh ----
    if (wave >= 2) {
        float* dst = lds_red + (wave - 2) * 2048;
#pragma unroll
        for (int rg = 0; rg < 16; ++rg) {
            const int el = (rg & 3) + 8 * (rg >> 2) + 4 * lh;
            dst[el * 64 + m]      = accA[rg];
            dst[el * 64 + 32 + m] = accB[rg];
        }
    }
    __syncthreads();
    if (wave < 2) {
        const float* srcr = lds_red + wave * 2048;
#pragma unroll
        for (int rg = 0; rg < 16; ++rg) {
            const int el = (rg & 3) + 8 * (rg >> 2) + 4 * lh;
            accA[rg] += srcr[el * 64 + m];
            accB[rg] += srcr[el * 64 + 32 + m];
        }
    }
    __syncthreads();
    if (wave == 1) {
#pragma unroll
        for (int rg = 0; rg < 16; ++rg) {
            const int el = (rg & 3) + 8 * (rg >> 2) + 4 * lh;
            lds_red[el * 64 + m]      = accA[rg];
            lds_red[el * 64 + 32 + m] = accB[rg];
        }
    }
    __syncthreads();
    if (wave == 0) {
        const float bA = b1[m], bB = b1[32 + m];
#pragma unroll
        for (int rg = 0; rg < 16; ++rg) {
            const int el = (rg & 3) + 8 * (rg >> 2) + 4 * lh;
            accA[rg] += lds_red[el * 64 + m];
            accB[rg] += lds_red[el * 64 + 32 + m];
        }
        // wave-0 LDS ops are in-order: reads above retire before these writes
#pragma unroll
        for (int rg = 0; rg < 16; ++rg) {
            const int el = (rg & 3) + 8 * (rg >> 2) + 4 * lh;
            lds_red[el * H1LD + m]      = ssp(accA[rg] + bA);
            lds_red[el * H1LD + 32 + m] = ssp(accB[rg] + bB);
        }
    }
    __syncthreads();

    // ---- tail: layers 2/3 (asy already in a register) ----
    const int b_local = tid >> 3;
    const int g       = tid & 7;
    const int b       = blockIdx.x * TB + b_local;
    asy = redg(asy);

    const float4* __restrict__ W2v = (const float4*)W2;
    const float4* __restrict__ b2v = (const float4*)b2;
    const int wbi = g * 2;
    const float4 b2a = b2v[wbi], b2b = b2v[wbi + 1];
    float s0 = b2a.x, s1 = b2a.y, s2 = b2a.z, s3 = b2a.w;
    float s4 = b2b.x, s5 = b2b.y, s6 = b2b.z, s7 = b2b.w;

    const float* __restrict__ h1row = lds_red + b_local * H1LD;
    for (int k = 0; k < HIDDEN; ++k) {
        const float hk  = h1row[k];
        const float4 wa = W2v[k * 16 + wbi];
        const float4 wb = W2v[k * 16 + wbi + 1];
        s0 = fmaf(hk, wa.x, s0); s1 = fmaf(hk, wa.y, s1);
        s2 = fmaf(hk, wa.z, s2); s3 = fmaf(hk, wa.w, s3);
        s4 = fmaf(hk, wb.x, s4); s5 = fmaf(hk, wb.y, s5);
        s6 = fmaf(hk, wb.z, s6); s7 = fmaf(hk, wb.w, s7);
    }

    const float4* __restrict__ W3v = (const float4*)W3;
    const float4 w3a = W3v[wbi], w3b = W3v[wbi + 1];
    float part = ssp(s0) * w3a.x + ssp(s1) * w3a.y
               + ssp(s2) * w3a.z + ssp(s3) * w3a.w
               + ssp(s4) * w3b.x + ssp(s5) * w3b.y
               + ssp(s6) * w3b.z + ssp(s7) * w3b.w;
    part = redg(part);

    if (g == 0) {
        const float ys = part + b3[0];
        out[b] = __expf(ys) * __expf(-asy);
    }
}

extern "C" void kernel_launch(void* const* d_in, const int* in_sizes, int n_in,
                              void* d_out, int out_size, void* d_ws, size_t ws_size,
                              hipStream_t stream) {
    const float* rs      = (const float*)d_in[0];
    const float* coords  = (const float*)d_in[1];
    const float* charges = (const float*)d_in[2];
    const float* W1      = (const float*)d_in[3];
    const float* b1      = (const float*)d_in[4];
    const float* W2      = (const float*)d_in[5];
    const float* b2      = (const float*)d_in[6];
    const float* W3      = (const float*)d_in[7];
    const float* b3      = (const float*)d_in[8];
    float* out = (float*)d_out;

    const int batch = in_sizes[0] / (N_EL * 3);   // 32768
    intx8* ws = (intx8*)d_ws;                     // 368 KB scratch (fp8 W1)

    prep_w1_kernel<<<N_PAIRS / 2, 256, 0, stream>>>(W1, ws);
    wfnet_kernel<<<batch / TB, BLOCK, 0, stream>>>(rs, coords, charges, ws,
                                                   b1, W2, b2, W3, b3, out);
}

// Round 15
// 146.997 us; speedup vs baseline: 1.4105x; 1.0755x over previous
//
#include <hip/hip_runtime.h>
#include <math.h>

#define N_EL    16
#define N_NUC   4
#define N_FEATS 32
#define N_PAIRS 184
#define HIDDEN  64
#define TB      32           // batch elements per block
#define BLOCK   256
#define DLD     185          // dist LDS stride
#define H1LD    68           // h1 stride in kernel 2
#define TPW     23           // K-tiles (2 pairs each) per wave; 4*23*2 = 184
#define WS_PART_OFF (1 << 19)   // partials start at 512 KB into d_ws

typedef int   intx8    __attribute__((ext_vector_type(8)));
typedef float floatx16 __attribute__((ext_vector_type(16)));

__device__ __forceinline__ float exp2_raw(float x) {
    float r;
    asm("v_exp_f32 %0, %1" : "=v"(r) : "v"(x));
    return r;
}

// triu_indices(16, 1)
__constant__ unsigned char c_I[120] = {
    0,0,0,0,0,0,0,0,0,0,0,0,0,0,0,
    1,1,1,1,1,1,1,1,1,1,1,1,1,1,
    2,2,2,2,2,2,2,2,2,2,2,2,2,
    3,3,3,3,3,3,3,3,3,3,3,3,
    4,4,4,4,4,4,4,4,4,4,4,
    5,5,5,5,5,5,5,5,5,5,
    6,6,6,6,6,6,6,6,6,
    7,7,7,7,7,7,7,7,
    8,8,8,8,8,8,8,
    9,9,9,9,9,9,
    10,10,10,10,10,
    11,11,11,11,
    12,12,12,
    13,13,
    14
};
__constant__ unsigned char c_J[120] = {
    1,2,3,4,5,6,7,8,9,10,11,12,13,14,15,
    2,3,4,5,6,7,8,9,10,11,12,13,14,15,
    3,4,5,6,7,8,9,10,11,12,13,14,15,
    4,5,6,7,8,9,10,11,12,13,14,15,
    5,6,7,8,9,10,11,12,13,14,15,
    6,7,8,9,10,11,12,13,14,15,
    7,8,9,10,11,12,13,14,15,
    8,9,10,11,12,13,14,15,
    9,10,11,12,13,14,15,
    10,11,12,13,14,15,
    11,12,13,14,15,
    12,13,14,15,
    13,14,15,
    14,15,
    15
};

__device__ __forceinline__ float ssp(float x) {
    float a = fabsf(x);
    return fmaxf(x, 0.0f) + log1pf(__expf(-a)) - 0.69314718056f;
}
__device__ __forceinline__ float redg(float v) {
    v += __shfl_xor(v, 1);
    v += __shfl_xor(v, 2);
    v += __shfl_xor(v, 4);
    return v;
}

// ---------------------------------------------------------------------------
// Prep (verified R14): W1 -> fp8 e4m3 (pre-scaled 2^6; MFMA applies 2^-6 via
// scale_b) in 32x32x64 B-fragment order.
// ---------------------------------------------------------------------------
__global__ __launch_bounds__(256)
void prep_w1_kernel(const float* __restrict__ W1, intx8* __restrict__ ws)
{
    __shared__ float w[2 * N_FEATS * HIDDEN];   // 16 KB: two pairs' rows
    const int t = blockIdx.x;
    const float* src = W1 + (size_t)(2 * t) * (N_FEATS * HIDDEN);
    for (int k = threadIdx.x; k < 2 * N_FEATS * HIDDEN; k += 256) w[k] = src[k];
    __syncthreads();

    const int tid = threadIdx.x;
    if (tid >= 128) return;
    const int lane = tid & 63;
    const int nh   = tid >> 6;
    const int lh   = lane >> 5;
    const int col  = nh * 32 + (lane & 31);
    const int fb   = lh * 16;
    intx8 frag;
#pragma unroll
    for (int r = 0; r < 8; ++r) {
        const int pair = r >> 2;
        const int fo   = fb + ((r & 3) << 2);
        const float v0 = 64.0f * w[(pair * N_FEATS + fo + 0) * 64 + col];
        const float v1 = 64.0f * w[(pair * N_FEATS + fo + 1) * 64 + col];
        const float v2 = 64.0f * w[(pair * N_FEATS + fo + 2) * 64 + col];
        const float v3 = 64.0f * w[(pair * N_FEATS + fo + 3) * 64 + col];
        int d = __builtin_amdgcn_cvt_pk_fp8_f32(v0, v1, 0, false);
        d     = __builtin_amdgcn_cvt_pk_fp8_f32(v2, v3, d, true);
        frag[r] = d;
    }
    ws[(size_t)(t * 2 + nh) * 64 + lane] = frag;
}

// ---------------------------------------------------------------------------
// Kernel 1 — GEMM ONLY (R15 split): phases 1-2 + fp8 K-loop, then each wave
// dumps its raw 32x64 partial to global. No reduction, no ssp, no tail, no
// post-loop barriers. R14 post-mortem: wall invariant to K-loop cost across
// 5 rounds -> isolate the K-loop to find out if it is the wall at all.
// ---------------------------------------------------------------------------
__global__ __launch_bounds__(BLOCK)
void wfnet_gemm(const float* __restrict__ rs,
                const float* __restrict__ coords,
                const intx8* __restrict__ ws,
                float* __restrict__ partials)
{
    __shared__ float lds_rs[TB * N_EL * 3];   // 6 KB
    __shared__ float lds_dist[TB * DLD];      // 23.7 KB

    const int tid  = threadIdx.x;
    const int wave = tid >> 6;               // = kh
    const int lane = tid & 63;
    const int m    = lane & 31;
    const int lh   = lane >> 5;

    // ---- phase 1: stage rs ----
    {
        const float* rs_blk = rs + (size_t)blockIdx.x * (TB * N_EL * 3);
        for (int k = tid; k < TB * N_EL * 3; k += BLOCK) lds_rs[k] = rs_blk[k];
    }
    __syncthreads();

    // ---- phase 2: distances only (asy moved to kernel 2) ----
    {
        const int bl = tid >> 3, g = tid & 7;
        const float* myrs = lds_rs + bl * (N_EL * 3);
        float* dst = lds_dist + bl * DLD;
        for (int i = 0; i < 8; ++i) {
            const int p = g + 8 * i;
            const int e = p >> 2, n = p & 3;
            const float dx = myrs[e * 3 + 0] - coords[n * 3 + 0];
            const float dy = myrs[e * 3 + 1] - coords[n * 3 + 1];
            const float dz = myrs[e * 3 + 2] - coords[n * 3 + 2];
            dst[p] = sqrtf(dx * dx + dy * dy + dz * dz);
        }
        for (int i = 0; i < 15; ++i) {
            const int q  = g + 8 * i;
            const int ei = 3 * (int)c_I[q], ej = 3 * (int)c_J[q];
            const float dx = myrs[ei + 0] - myrs[ej + 0];
            const float dy = myrs[ei + 1] - myrs[ej + 1];
            const float dz = myrs[ei + 2] - myrs[ej + 2];
            dst[64 + q] = sqrtf(dx * dx + dy * dy + dz * dz);
        }
    }
    __syncthreads();

    // per-lane Gaussian constants for feats lh*16 .. lh*16+15
    const int f0 = lh * 16;
#define MKC(P, FF) float P##1, P##0; { \
    const float fq = (float)(FF) * (1.0f / 31.0f); \
    const float mu = 10.0f * fq * fq; \
    const float is = 7.0f / (1.0f + 10.0f * fq); \
    P##1 = is * 1.2011224087864498f; \
    P##0 = -mu * P##1; }
    MKC(F0_,  f0 + 0)  MKC(F1_,  f0 + 1)  MKC(F2_,  f0 + 2)  MKC(F3_,  f0 + 3)
    MKC(F4_,  f0 + 4)  MKC(F5_,  f0 + 5)  MKC(F6_,  f0 + 6)  MKC(F7_,  f0 + 7)
    MKC(F8_,  f0 + 8)  MKC(F9_,  f0 + 9)  MKC(F10_, f0 + 10) MKC(F11_, f0 + 11)
    MKC(F12_, f0 + 12) MKC(F13_, f0 + 13) MKC(F14_, f0 + 14) MKC(F15_, f0 + 15)
#undef MKC

    floatx16 accA = {};
    floatx16 accB = {};
    const intx8* wq = ws + ((size_t)(wave * TPW) * 128 + lane);
    const float* drow = lds_dist + m * DLD + wave * (2 * TPW);

#define XO(dd, P) ({ const float t_ = fmaf(dd, P##1, P##0); exp2_raw(t_ * -t_); })
#define MKA8(AV, dx0, dx1) \
    intx8 AV; { int dw_; \
    dw_   = __builtin_amdgcn_cvt_pk_fp8_f32(XO(dx0,F0_),  XO(dx0,F1_),  0,  false); \
    AV[0] = __builtin_amdgcn_cvt_pk_fp8_f32(XO(dx0,F2_),  XO(dx0,F3_),  dw_, true); \
    dw_   = __builtin_amdgcn_cvt_pk_fp8_f32(XO(dx0,F4_),  XO(dx0,F5_),  0,  false); \
    AV[1] = __builtin_amdgcn_cvt_pk_fp8_f32(XO(dx0,F6_),  XO(dx0,F7_),  dw_, true); \
    dw_   = __builtin_amdgcn_cvt_pk_fp8_f32(XO(dx0,F8_),  XO(dx0,F9_),  0,  false); \
    AV[2] = __builtin_amdgcn_cvt_pk_fp8_f32(XO(dx0,F10_), XO(dx0,F11_), dw_, true); \
    dw_   = __builtin_amdgcn_cvt_pk_fp8_f32(XO(dx0,F12_), XO(dx0,F13_), 0,  false); \
    AV[3] = __builtin_amdgcn_cvt_pk_fp8_f32(XO(dx0,F14_), XO(dx0,F15_), dw_, true); \
    dw_   = __builtin_amdgcn_cvt_pk_fp8_f32(XO(dx1,F0_),  XO(dx1,F1_),  0,  false); \
    AV[4] = __builtin_amdgcn_cvt_pk_fp8_f32(XO(dx1,F2_),  XO(dx1,F3_),  dw_, true); \
    dw_   = __builtin_amdgcn_cvt_pk_fp8_f32(XO(dx1,F4_),  XO(dx1,F5_),  0,  false); \
    AV[5] = __builtin_amdgcn_cvt_pk_fp8_f32(XO(dx1,F6_),  XO(dx1,F7_),  dw_, true); \
    dw_   = __builtin_amdgcn_cvt_pk_fp8_f32(XO(dx1,F8_),  XO(dx1,F9_),  0,  false); \
    AV[6] = __builtin_amdgcn_cvt_pk_fp8_f32(XO(dx1,F10_), XO(dx1,F11_), dw_, true); \
    dw_   = __builtin_amdgcn_cvt_pk_fp8_f32(XO(dx1,F12_), XO(dx1,F13_), 0,  false); \
    AV[7] = __builtin_amdgcn_cvt_pk_fp8_f32(XO(dx1,F14_), XO(dx1,F15_), dw_, true); }
#define KROUND(AV, Q0, Q1) { \
    accA = __builtin_amdgcn_mfma_scale_f32_32x32x64_f8f6f4( \
               AV, Q0, accA, 0, 0, 0, 0x7F7F7F7F, 0, 0x79797979); \
    accB = __builtin_amdgcn_mfma_scale_f32_32x32x64_f8f6f4( \
               AV, Q1, accB, 0, 0, 0, 0x7F7F7F7F, 0, 0x79797979); }

    intx8 pA0 = wq[0],   pA1 = wq[64];
    intx8 pB0 = wq[128], pB1 = wq[192];
    float dA0 = drow[0], dA1 = drow[1];
    float dB0 = drow[2], dB1 = drow[3];

    for (int it = 0; it < 10; ++it) {
        const intx8* wn = wq + 256;
        const float eA0 = drow[4 * it + 4], eA1 = drow[4 * it + 5];
        const float eB0 = drow[4 * it + 6], eB1 = drow[4 * it + 7];

        { MKA8(av, dA0, dA1) KROUND(av, pA0, pA1) }
        pA0 = wn[0]; pA1 = wn[64];

        { MKA8(bv, dB0, dB1) KROUND(bv, pB0, pB1) }
        pB0 = wn[128]; pB1 = wn[192];

        wq = wn;
        dA0 = eA0; dA1 = eA1; dB0 = eB0; dB1 = eB1;
    }
    {
        const intx8* wn = wq + 256;
        const float eA0 = drow[44], eA1 = drow[45];
        { MKA8(av, dA0, dA1) KROUND(av, pA0, pA1) }
        pA0 = wn[0]; pA1 = wn[64];
        { MKA8(bv, dB0, dB1) KROUND(bv, pB0, pB1) }
        { MKA8(cv, eA0, eA1) KROUND(cv, pA0, pA1) }
    }
#undef KROUND
#undef MKA8
#undef XO

    // ---- dump raw partial to global, no barrier. C/D layout:
    //      col = lane&31 (+32 for B), row el = (rg&3) + 8*(rg>>2) + 4*lh ----
    float* pdst = partials + ((size_t)blockIdx.x * 4 + wave) * 2048;
#pragma unroll
    for (int rg = 0; rg < 16; ++rg) {
        const int el = (rg & 3) + 8 * (rg >> 2) + 4 * lh;
        pdst[el * 64 + m]      = accA[rg];
        pdst[el * 64 + 32 + m] = accB[rg];
    }
}

// ---------------------------------------------------------------------------
// Kernel 2 — tail: sum 4 partials + b1 + ssp -> h1 (LDS) -> layers 2/3 +
// asy (nuc dists recomputed) + output. Low VGPR/LDS -> high occupancy.
// ---------------------------------------------------------------------------
__global__ __launch_bounds__(BLOCK)
void wfnet_tail(const float* __restrict__ rs,
                const float* __restrict__ coords,
                const float* __restrict__ charges,
                const float* __restrict__ partials,
                const float* __restrict__ b1,
                const float* __restrict__ W2,
                const float* __restrict__ b2,
                const float* __restrict__ W3,
                const float* __restrict__ b3,
                float* __restrict__ out)
{
    __shared__ float lds_rs[TB * N_EL * 3];   // 6 KB
    __shared__ float lds_h1[TB * H1LD];       // 8.7 KB

    const int tid = threadIdx.x;
    const int el  = tid >> 3;                // 0..31
    const int g   = tid & 7;
    const int b   = blockIdx.x * TB + el;

    // stage rs for asy
    {
        const float* rs_blk = rs + (size_t)blockIdx.x * (TB * N_EL * 3);
        for (int k = tid; k < TB * N_EL * 3; k += BLOCK) lds_rs[k] = rs_blk[k];
    }

    // sum 4 wave-partials for (el, cols g*8..g*8+7), + b1, ssp -> LDS h1
    {
        const float* pb = partials + (size_t)blockIdx.x * 8192 + el * 64 + g * 8;
        const float4 p00 = ((const float4*)(pb + 0 * 2048))[0];
        const float4 p01 = ((const float4*)(pb + 0 * 2048))[1];
        const float4 p10 = ((const float4*)(pb + 1 * 2048))[0];
        const float4 p11 = ((const float4*)(pb + 1 * 2048))[1];
        const float4 p20 = ((const float4*)(pb + 2 * 2048))[0];
        const float4 p21 = ((const float4*)(pb + 2 * 2048))[1];
        const float4 p30 = ((const float4*)(pb + 3 * 2048))[0];
        const float4 p31 = ((const float4*)(pb + 3 * 2048))[1];
        const float4 ba = ((const float4*)(b1 + g * 8))[0];
        const float4 bb = ((const float4*)(b1 + g * 8))[1];
        float* h1w = lds_h1 + el * H1LD + g * 8;
        h1w[0] = ssp(p00.x + p10.x + p20.x + p30.x + ba.x);
        h1w[1] = ssp(p00.y + p10.y + p20.y + p30.y + ba.y);
        h1w[2] = ssp(p00.z + p10.z + p20.z + p30.z + ba.z);
        h1w[3] = ssp(p00.w + p10.w + p20.w + p30.w + ba.w);
        h1w[4] = ssp(p01.x + p11.x + p21.x + p31.x + bb.x);
        h1w[5] = ssp(p01.y + p11.y + p21.y + p31.y + bb.y);
        h1w[6] = ssp(p01.z + p11.z + p21.z + p31.z + bb.z);
        h1w[7] = ssp(p01.w + p11.w + p21.w + p31.w + bb.w);
    }

    // asy partial: this thread's 8 el-nuc pairs (needs only lds_rs)
    float asy = 0.0f;
    __syncthreads();   // rs staged AND h1 visible
    {
        const float* myrs = lds_rs + el * (N_EL * 3);
        const float4 ch = *(const float4*)charges;
#pragma unroll
        for (int i = 0; i < 8; ++i) {
            const int p = g + 8 * i;
            const int e = p >> 2, n = p & 3;
            const float dx = myrs[e * 3 + 0] - coords[n * 3 + 0];
            const float dy = myrs[e * 3 + 1] - coords[n * 3 + 1];
            const float dz = myrs[e * 3 + 2] - coords[n * 3 + 2];
            const float d = sqrtf(dx * dx + dy * dy + dz * dz);
            const float Z = (n < 2) ? ((n == 0) ? ch.x : ch.y)
                                    : ((n == 2) ? ch.z : ch.w);
            asy += (Z * d + d * d) / (1.0f + d);   // decay = sqrt(2*0.5) = 1
        }
    }
    asy = redg(asy);

    // layers 2/3 (R14-verified structure)
    const float4* __restrict__ W2v = (const float4*)W2;
    const float4* __restrict__ b2v = (const float4*)b2;
    const int wbi = g * 2;
    const float4 b2a = b2v[wbi], b2b = b2v[wbi + 1];
    float s0 = b2a.x, s1 = b2a.y, s2 = b2a.z, s3 = b2a.w;
    float s4 = b2b.x, s5 = b2b.y, s6 = b2b.z, s7 = b2b.w;

    const float* __restrict__ h1row = lds_h1 + el * H1LD;
    for (int k = 0; k < HIDDEN; ++k) {
        const float hk  = h1row[k];
        const float4 wa = W2v[k * 16 + wbi];
        const float4 wb = W2v[k * 16 + wbi + 1];
        s0 = fmaf(hk, wa.x, s0); s1 = fmaf(hk, wa.y, s1);
        s2 = fmaf(hk, wa.z, s2); s3 = fmaf(hk, wa.w, s3);
        s4 = fmaf(hk, wb.x, s4); s5 = fmaf(hk, wb.y, s5);
        s6 = fmaf(hk, wb.z, s6); s7 = fmaf(hk, wb.w, s7);
    }

    const float4* __restrict__ W3v = (const float4*)W3;
    const float4 w3a = W3v[wbi], w3b = W3v[wbi + 1];
    float part = ssp(s0) * w3a.x + ssp(s1) * w3a.y
               + ssp(s2) * w3a.z + ssp(s3) * w3a.w
               + ssp(s4) * w3b.x + ssp(s5) * w3b.y
               + ssp(s6) * w3b.z + ssp(s7) * w3b.w;
    part = redg(part);

    if (g == 0) {
        const float ys = part + b3[0];
        out[b] = __expf(ys) * __expf(-asy);
    }
}

extern "C" void kernel_launch(void* const* d_in, const int* in_sizes, int n_in,
                              void* d_out, int out_size, void* d_ws, size_t ws_size,
                              hipStream_t stream) {
    const float* rs      = (const float*)d_in[0];
    const float* coords  = (const float*)d_in[1];
    const float* charges = (const float*)d_in[2];
    const float* W1      = (const float*)d_in[3];
    const float* b1      = (const float*)d_in[4];
    const float* W2      = (const float*)d_in[5];
    const float* b2      = (const float*)d_in[6];
    const float* W3      = (const float*)d_in[7];
    const float* b3      = (const float*)d_in[8];
    float* out = (float*)d_out;

    const int batch = in_sizes[0] / (N_EL * 3);   // 32768
    intx8* w1f8     = (intx8*)d_ws;               // 368 KB fp8 W1
    float* partials = (float*)((char*)d_ws + WS_PART_OFF);  // 32 MB

    prep_w1_kernel<<<N_PAIRS / 2, 256, 0, stream>>>(W1, w1f8);
    wfnet_gemm<<<batch / TB, BLOCK, 0, stream>>>(rs, coords, w1f8, partials);
    wfnet_tail<<<batch / TB, BLOCK, 0, stream>>>(rs, coords, charges, partials,
                                                 b1, W2, b2, W3, b3, out);
}